// Round 10
// baseline (134.723 us; speedup 1.0000x reference)
//
#include <hip/hip_runtime.h>
#include <math.h>

#define IMG_H 512
#define IMG_W 512
#define PSIZE 512
#define NIMG 16
#define NBOX 16
#define RED_BLOCKS 256
#define Z0 8              // z-split for j=-1 (full-rect) tasks
#define ZJ 4              // z-split for j>=0 (intersection) tasks
#define SLOTS 72          // Z0 + NBOX*ZJ partial slots per (b,i)

// workspace layout (float indices; 16B-aligned where int4 access occurs)
#define WS_PMEAN 0                            // 3
#define WS_PSTD  3                            // 3
#define WS_PART  6                            // RED_BLOCKS*6 = 1536
#define WS_GEO   1544                         // 256 * int4 (1024 ints)
#define WS_TASK  2568                         // 4352 * 8 ints
#define WS_PAIR  37384                        // 256 * SLOTS * 8 floats
#define WS_COEF  (WS_PAIR + 256 * SLOTS * 8)  // 256 * 8 floats

struct BoxGeo { int y0, x0, ph, pw, valid; };

__device__ __forceinline__ BoxGeo make_geo(const float* bx) {
    float ymin = bx[0], xmin = bx[1], ymax = bx[2], xmax = bx[3];
    float h = ymax - ymin, w = xmax - xmin;
    float pwf = h * 0.3f;            // SCALE
    float phf = 1.0f * pwf;          // ASPECT * pw
    float oy = ymin + h * 0.5f;
    float ox = xmin + w * 0.5f;
    float yp = fmaxf(oy - phf * 0.5f, 0.0f);
    float xp = fmaxf(ox - pwf * 0.5f, 0.0f);
    if (yp + phf > (float)IMG_H) yp = (float)IMG_H - phf;
    if (xp + pwf > (float)IMG_W) xp = (float)IMG_W - pwf;
    BoxGeo g;
    g.y0 = (int)yp; g.x0 = (int)xp;   // tf.cast truncation
    g.ph = (int)phf; g.pw = (int)pwf;
    g.valid = (phf > 60.0f) ? 1 : 0;  // MIN_PATCH_H tested on float ph
    return g;
}

__device__ __forceinline__ void bsample(const float* __restrict__ patch,
                                        int relY, int relX, float phf, float pwf,
                                        float s[3]) {
    float sy = ((float)relY + 0.5f) * (float)PSIZE / phf - 0.5f;
    sy = fminf(fmaxf(sy, 0.0f), (float)(PSIZE - 1));
    float sx = ((float)relX + 0.5f) * (float)PSIZE / pwf - 0.5f;
    sx = fminf(fmaxf(sx, 0.0f), (float)(PSIZE - 1));
    int y0 = (int)floorf(sy);
    int y1 = min(y0 + 1, PSIZE - 1);
    int x0 = (int)floorf(sx);
    int x1 = min(x0 + 1, PSIZE - 1);
    float wy = sy - (float)y0;
    float wx = sx - (float)x0;
    const float* p00 = patch + (y0 * PSIZE + x0) * 3;
    const float* p01 = patch + (y0 * PSIZE + x1) * 3;
    const float* p10 = patch + (y1 * PSIZE + x0) * 3;
    const float* p11 = patch + (y1 * PSIZE + x1) * 3;
#pragma unroll
    for (int c = 0; c < 3; ++c) {
        float top = (1.f - wx) * p00[c] + wx * p01[c];
        float bot = (1.f - wx) * p10[c] + wx * p11[c];
        s[c] = (1.f - wy) * top + wy * bot;
    }
}

template<int N, int NWAVES>
__device__ __forceinline__ void block_reduceN(float v[N]) {
    __shared__ float lds[NWAVES][N];
    const int lane = threadIdx.x & 63;
    const int wave = threadIdx.x >> 6;
    __syncthreads();
#pragma unroll
    for (int k = 0; k < N; ++k) {
#pragma unroll
        for (int off = 32; off > 0; off >>= 1)
            v[k] += __shfl_down(v[k], off, 64);
    }
    if (lane == 0) {
#pragma unroll
        for (int k = 0; k < N; ++k) lds[wave][k] = v[k];
    }
    __syncthreads();
    if (wave == 0) {
#pragma unroll
        for (int k = 0; k < N; ++k) {
            float x = (lane < NWAVES) ? lds[lane][k] : 0.0f;
#pragma unroll
            for (int off = 32; off > 0; off >>= 1)
                x += __shfl_down(x, off, 64);
            if (lane == 0) lds[0][k] = x;
        }
    }
    __syncthreads();
#pragma unroll
    for (int k = 0; k < N; ++k) v[k] = lds[0][k];
}

// ---------------------------------------------------------------------------
// setup_geo: geo table (int4 per (b,i): {y0, x0, valid?ph:-1, pw}) and task
// descriptors per (b,i,j_idx): {ry0, rx0, rw, rh, jy0, jx0, jph(-1=image), jpw}
// ---------------------------------------------------------------------------
__global__ void setup_geo(const float* __restrict__ boxes,
                          float* __restrict__ ws) {
    int* iws = (int*)ws;
    const int tid = threadIdx.x;
    if (tid < NIMG * NBOX) {
        BoxGeo g = make_geo(boxes + tid * 4);
        ((int4*)(iws + WS_GEO))[tid] =
            make_int4(g.y0, g.x0, g.valid ? g.ph : -1, g.pw);
    }
    for (int t = tid; t < NIMG * NBOX * 17; t += 256) {
        const int bi = t / 17, j_idx = t % 17;
        const int b = bi >> 4, i = bi & 15;
        int d[8] = {0, 0, 0, 0, 0, 0, -1, 0};
        if (j_idx <= i) {
            BoxGeo gi = make_geo(boxes + (b * NBOX + i) * 4);
            if (gi.valid) {
                int ry0 = gi.y0, rx0 = gi.x0;
                int ry1 = gi.y0 + gi.ph, rx1 = gi.x0 + gi.pw;
                bool ok = true;
                if (j_idx >= 1) {
                    BoxGeo gj = make_geo(boxes + (b * NBOX + j_idx - 1) * 4);
                    if (!gj.valid) ok = false;
                    else {
                        ry0 = max(ry0, gj.y0); rx0 = max(rx0, gj.x0);
                        ry1 = min(ry1, gj.y0 + gj.ph);
                        rx1 = min(rx1, gj.x0 + gj.pw);
                        d[4] = gj.y0; d[5] = gj.x0; d[6] = gj.ph; d[7] = gj.pw;
                    }
                }
                if (ok && ry1 > ry0 && rx1 > rx0) {
                    d[0] = ry0; d[1] = rx0; d[2] = rx1 - rx0; d[3] = ry1 - ry0;
                }
            }
        }
        int* o = iws + WS_TASK + t * 8;
#pragma unroll
        for (int k = 0; k < 8; ++k) o[k] = d[k];
    }
}

// ---------------------------------------------------------------------------
// patch mean/std
// ---------------------------------------------------------------------------
__global__ void patch_stats_partial(const float* __restrict__ patch,
                                    float* __restrict__ ws) {
    const int g = blockIdx.x * 256 + threadIdx.x;
    const float4* p4 = (const float4*)patch;
    float4 a = p4[3 * g], b = p4[3 * g + 1], c = p4[3 * g + 2];
    float v[6];
    v[0] = a.x + a.w + b.z + c.y;
    v[1] = a.y + b.x + b.w + c.z;
    v[2] = a.z + b.y + c.x + c.w;
    v[3] = a.x*a.x + a.w*a.w + b.z*b.z + c.y*c.y;
    v[4] = a.y*a.y + b.x*b.x + b.w*b.w + c.z*c.z;
    v[5] = a.z*a.z + b.y*b.y + c.x*c.x + c.w*c.w;
    block_reduceN<6, 4>(v);
    if (threadIdx.x == 0) {
        float* o = ws + WS_PART + blockIdx.x * 6;
#pragma unroll
        for (int k = 0; k < 6; ++k) o[k] = v[k];
    }
}

__global__ void patch_stats_final(float* __restrict__ ws) {
    float v[6];
    const float* p = ws + WS_PART + threadIdx.x * 6;
#pragma unroll
    for (int k = 0; k < 6; ++k) v[k] = p[k];
    block_reduceN<6, 4>(v);
    if (threadIdx.x == 0) {
        const float n = (float)(PSIZE * PSIZE);
#pragma unroll
        for (int c = 0; c < 3; ++c) {
            float m = v[c] / n;
            float var = v[3 + c] / n - m * m;
            ws[WS_PMEAN + c] = m;
            ws[WS_PSTD + c] = sqrtf(fmaxf(var, 0.f)) + 1e-6f;
        }
    }
}

// ---------------------------------------------------------------------------
// pair_sums v3: descriptor-driven; empty tasks exit on one L2 load.
// ---------------------------------------------------------------------------
__launch_bounds__(256)
__global__ void pair_sums(const float* __restrict__ images,
                          const float* __restrict__ patch,
                          float* __restrict__ ws) {
    const int bi = blockIdx.x, j_idx = blockIdx.y, z = blockIdx.z;
    const int i = bi & 15;
    if (j_idx > i) return;
    if (j_idx >= 1 && z >= ZJ) return;
    const int* iws = (const int*)ws;
    const int* d = iws + WS_TASK + (bi * 17 + j_idx) * 8;
    const int rw = d[2];
    if (rw <= 0) return;
    const int ry0 = d[0], rx0 = d[1], rh = d[3];
    const int jy0 = d[4], jx0 = d[5], jph = d[6], jpw = d[7];

    __shared__ int4 sgeo[NBOX];
    if (threadIdx.x < NBOX)
        sgeo[threadIdx.x] =
            ((const int4*)(iws + WS_GEO))[(bi >> 4) * NBOX + threadIdx.x];
    __syncthreads();

    const int n = rw * rh;
    const float* img = images + (size_t)(bi >> 4) * IMG_H * IMG_W * 3;
    const float jphf = (float)jph, jpwf = (float)jpw;
    const int nz = (j_idx == 0) ? Z0 : ZJ;

    float v[7] = {0.f, 0.f, 0.f, 0.f, 0.f, 0.f, 0.f};
    for (int t = z * 256 + threadIdx.x; t < n; t += 256 * nz) {
        const int y = ry0 + t / rw;
        const int x = rx0 + t % rw;
        bool inc = true;
        for (int k = j_idx; k < i; ++k) {         // k = j+1 .. i-1
            const int4 g = sgeo[k];
            if (g.z > 0 && y >= g.x && y < g.x + g.z &&
                x >= g.y && x < g.y + g.w) { inc = false; break; }
        }
        if (inc) {
            float s[3];
            if (jph > 0) {
                bsample(patch, y - jy0, x - jx0, jphf, jpwf, s);
            } else {
                const float* p = img + ((size_t)y * IMG_W + x) * 3;
                s[0] = p[0]; s[1] = p[1]; s[2] = p[2];
            }
            v[0] += 1.f;
            v[1] += s[0]; v[2] += s[1]; v[3] += s[2];
            v[4] += s[0]*s[0]; v[5] += s[1]*s[1]; v[6] += s[2]*s[2];
        }
    }
    block_reduceN<7, 4>(v);
    if (threadIdx.x == 0) {
        const int slot = (j_idx == 0) ? z : (Z0 + (j_idx - 1) * ZJ + z);
        float* o = ws + WS_PAIR + ((size_t)bi * SLOTS + slot) * 8;
#pragma unroll
        for (int k = 0; k < 7; ++k) o[k] = v[k];
    }
}

// ---------------------------------------------------------------------------
// solve_coeffs: per-image 16-step recurrence. One wave per image.
// ---------------------------------------------------------------------------
__global__ void solve_coeffs(const float* __restrict__ boxes,
                             float* __restrict__ ws) {
    const int b = blockIdx.x;
    const int lane = threadIdx.x;       // 64 threads = 1 wave

    BoxGeo g = make_geo(boxes + (b * NBOX + (lane < NBOX ? lane : NBOX - 1)) * 4);
    float pm[3], ps[3];
#pragma unroll
    for (int c = 0; c < 3; ++c) { pm[c] = ws[WS_PMEAN + c]; ps[c] = ws[WS_PSTD + c]; }

    float sc[3] = {0.f, 0.f, 0.f}, of[3] = {0.f, 0.f, 0.f};

    for (int i = 0; i < NBOX; ++i) {
        const int valid_i = __shfl(g.valid, i, 64);
        if (!valid_i) continue;

        float cnt = 0.f, s1[3] = {0.f,0.f,0.f}, s2[3] = {0.f,0.f,0.f};
        if (lane <= i) {
            const int slot0 = (lane == 0) ? 0 : (Z0 + (lane - 1) * ZJ);
            const int nz = (lane == 0) ? Z0 : ZJ;
            const float* p = ws + WS_PAIR +
                ((size_t)(b * NBOX + i) * SLOTS + slot0) * 8;
            for (int zz = 0; zz < nz; ++zz) {
                cnt   += p[zz*8 + 0];
                s1[0] += p[zz*8 + 1]; s1[1] += p[zz*8 + 2]; s1[2] += p[zz*8 + 3];
                s2[0] += p[zz*8 + 4]; s2[1] += p[zz*8 + 5]; s2[2] += p[zz*8 + 6];
            }
        }
        float ts[3], tq[3];
#pragma unroll
        for (int c = 0; c < 3; ++c) {
            if (lane == 0) { ts[c] = s1[c]; tq[c] = s2[c]; }
            else {
                ts[c] = sc[c] * s1[c] + of[c] * cnt;
                tq[c] = sc[c]*sc[c]*s2[c] + 2.f*sc[c]*of[c]*s1[c] + of[c]*of[c]*cnt;
            }
        }
#pragma unroll
        for (int c = 0; c < 3; ++c) {
#pragma unroll
            for (int off = 16; off > 0; off >>= 1) {
                ts[c] += __shfl_down(ts[c], off, 32);
                tq[c] += __shfl_down(tq[c], off, 32);
            }
        }
        const int phi = __shfl(g.ph, i, 64);
        const int pwi = __shfl(g.pw, i, 64);
        const float cntf = fmaxf((float)(phi * pwi), 1.0f);
        float nsc[3] = {0.f,0.f,0.f}, nof[3] = {0.f,0.f,0.f};
        if (lane == 0) {
#pragma unroll
            for (int c = 0; c < 3; ++c) {
                float mean = ts[c] / cntf;
                float var = tq[c] / cntf - mean * mean;
                float sd = sqrtf(fmaxf(var, 0.f)) + 1e-6f;
                nsc[c] = sd / ps[c];
                nof[c] = mean - pm[c] * nsc[c];
            }
        }
#pragma unroll
        for (int c = 0; c < 3; ++c) {
            float bs = __shfl(nsc[c], 0, 64);
            float bo = __shfl(nof[c], 0, 64);
            if (lane == i + 1) { sc[c] = bs; of[c] = bo; }
            if (lane == 0) {
                ws[WS_COEF + (size_t)(b * NBOX + i) * 8 + c] = bs;
                ws[WS_COEF + (size_t)(b * NBOX + i) * 8 + 3 + c] = bo;
            }
        }
    }
}

// ---------------------------------------------------------------------------
// decal: write only covered pixels. Block (bi, z): pixels of rect_i not
// covered by any later valid box (those are written by that box's decal).
// Mutually exclusive writes -> deterministic.
// ---------------------------------------------------------------------------
__launch_bounds__(256)
__global__ void decal(const float* __restrict__ patch,
                      const float* __restrict__ ws,
                      float* __restrict__ out) {
    const int bi = blockIdx.x;
    const int b = bi >> 4, i = bi & 15;
    const int* iws = (const int*)ws;
    __shared__ int4 sgeo[NBOX];
    __shared__ float scoef[6];
    if (threadIdx.x < NBOX)
        sgeo[threadIdx.x] = ((const int4*)(iws + WS_GEO))[b * NBOX + threadIdx.x];
    if (threadIdx.x >= 32 && threadIdx.x < 38)
        scoef[threadIdx.x - 32] = ws[WS_COEF + (size_t)bi * 8 + (threadIdx.x - 32)];
    __syncthreads();
    const int4 gi = sgeo[i];
    if (gi.z <= 0) return;                     // invalid patch
    const int y0 = gi.x, x0 = gi.y, ph = gi.z, pw = gi.w;
    const int n = ph * pw;
    const float phf = (float)ph, pwf = (float)pw;
    float* img = out + (size_t)b * IMG_H * IMG_W * 3;

    for (int t = blockIdx.y * 256 + threadIdx.x; t < n; t += 256 * 8) {
        const int y = y0 + t / pw;
        const int x = x0 + t % pw;
        bool cov = false;
        for (int k = i + 1; k < NBOX; ++k) {
            const int4 g = sgeo[k];
            if (g.z > 0 && y >= g.x && y < g.x + g.z &&
                x >= g.y && x < g.y + g.w) { cov = true; break; }
        }
        if (!cov) {
            float s[3];
            bsample(patch, y - y0, x - x0, phf, pwf, s);
            float* o = img + ((size_t)y * IMG_W + x) * 3;
            o[0] = s[0] * scoef[0] + scoef[3];
            o[1] = s[1] * scoef[1] + scoef[4];
            o[2] = s[2] * scoef[2] + scoef[5];
        }
    }
}

extern "C" void kernel_launch(void* const* d_in, const int* in_sizes, int n_in,
                              void* d_out, int out_size, void* d_ws, size_t ws_size,
                              hipStream_t stream) {
    const float* images = (const float*)d_in[0];
    const float* boxes  = (const float*)d_in[1];
    const float* patch  = (const float*)d_in[2];
    float* out = (float*)d_out;
    float* ws  = (float*)d_ws;

    // zero the pair-partials region (empty tasks write nothing)
    hipMemsetAsync(ws + WS_PAIR, 0, (size_t)256 * SLOTS * 8 * sizeof(float), stream);
    setup_geo<<<1, 256, 0, stream>>>(boxes, ws);
    patch_stats_partial<<<RED_BLOCKS, 256, 0, stream>>>(patch, ws);
    patch_stats_final<<<1, RED_BLOCKS, 0, stream>>>(ws);
    // background copy: pure streaming at ~full HBM BW
    hipMemcpyAsync(out, images, (size_t)NIMG * IMG_H * IMG_W * 3 * sizeof(float),
                   hipMemcpyDeviceToDevice, stream);
    pair_sums<<<dim3(NIMG * NBOX, 17, Z0), 256, 0, stream>>>(images, patch, ws);
    solve_coeffs<<<NIMG, 64, 0, stream>>>(boxes, ws);
    decal<<<dim3(NIMG * NBOX, 8), 256, 0, stream>>>(patch, ws, out);
}

// Round 11
// 130.758 us; speedup vs baseline: 1.0303x; 1.0303x over previous
//
#include <hip/hip_runtime.h>
#include <math.h>

#define IMG_H 512
#define IMG_W 512
#define PSIZE 512
#define NIMG 16
#define NBOX 16
#define RED_BLOCKS 256
#define Z0 8              // z-split for j=-1 (full-rect) tasks
#define ZJ 4              // z-split for j>=0 (intersection) tasks
#define SLOTS 72          // Z0 + NBOX*ZJ partial slots per (b,i)

// workspace layout (float indices; 16B-aligned where int4 access occurs)
#define WS_PMEAN 0                            // 3
#define WS_PSTD  3                            // 3
#define WS_PART  6                            // RED_BLOCKS*6 = 1536
#define WS_GEO   1544                         // 256 * int4 (1024 ints)
#define WS_TASK  2568                         // 4352 * 8 ints
#define WS_PAIR  37384                        // 256 * SLOTS * 8 floats
#define WS_COEF  (WS_PAIR + 256 * SLOTS * 8)  // 256 * 8 floats

struct BoxGeo { int y0, x0, ph, pw, valid; };

__device__ __forceinline__ BoxGeo make_geo(const float* bx) {
    float ymin = bx[0], xmin = bx[1], ymax = bx[2], xmax = bx[3];
    float h = ymax - ymin, w = xmax - xmin;
    float pwf = h * 0.3f;            // SCALE
    float phf = 1.0f * pwf;          // ASPECT * pw
    float oy = ymin + h * 0.5f;
    float ox = xmin + w * 0.5f;
    float yp = fmaxf(oy - phf * 0.5f, 0.0f);
    float xp = fmaxf(ox - pwf * 0.5f, 0.0f);
    if (yp + phf > (float)IMG_H) yp = (float)IMG_H - phf;
    if (xp + pwf > (float)IMG_W) xp = (float)IMG_W - pwf;
    BoxGeo g;
    g.y0 = (int)yp; g.x0 = (int)xp;   // tf.cast truncation
    g.ph = (int)phf; g.pw = (int)pwf;
    g.valid = (phf > 60.0f) ? 1 : 0;  // MIN_PATCH_H tested on float ph
    return g;
}

__device__ __forceinline__ void bsample(const float* __restrict__ patch,
                                        int relY, int relX, float phf, float pwf,
                                        float s[3]) {
    float sy = ((float)relY + 0.5f) * (float)PSIZE / phf - 0.5f;
    sy = fminf(fmaxf(sy, 0.0f), (float)(PSIZE - 1));
    float sx = ((float)relX + 0.5f) * (float)PSIZE / pwf - 0.5f;
    sx = fminf(fmaxf(sx, 0.0f), (float)(PSIZE - 1));
    int y0 = (int)floorf(sy);
    int y1 = min(y0 + 1, PSIZE - 1);
    int x0 = (int)floorf(sx);
    int x1 = min(x0 + 1, PSIZE - 1);
    float wy = sy - (float)y0;
    float wx = sx - (float)x0;
    const float* p00 = patch + (y0 * PSIZE + x0) * 3;
    const float* p01 = patch + (y0 * PSIZE + x1) * 3;
    const float* p10 = patch + (y1 * PSIZE + x0) * 3;
    const float* p11 = patch + (y1 * PSIZE + x1) * 3;
#pragma unroll
    for (int c = 0; c < 3; ++c) {
        float top = (1.f - wx) * p00[c] + wx * p01[c];
        float bot = (1.f - wx) * p10[c] + wx * p11[c];
        s[c] = (1.f - wy) * top + wy * bot;
    }
}

template<int N, int NWAVES>
__device__ __forceinline__ void block_reduceN(float v[N]) {
    __shared__ float lds[NWAVES][N];
    const int lane = threadIdx.x & 63;
    const int wave = threadIdx.x >> 6;
    __syncthreads();
#pragma unroll
    for (int k = 0; k < N; ++k) {
#pragma unroll
        for (int off = 32; off > 0; off >>= 1)
            v[k] += __shfl_down(v[k], off, 64);
    }
    if (lane == 0) {
#pragma unroll
        for (int k = 0; k < N; ++k) lds[wave][k] = v[k];
    }
    __syncthreads();
    if (wave == 0) {
#pragma unroll
        for (int k = 0; k < N; ++k) {
            float x = (lane < NWAVES) ? lds[lane][k] : 0.0f;
#pragma unroll
            for (int off = 32; off > 0; off >>= 1)
                x += __shfl_down(x, off, 64);
            if (lane == 0) lds[0][k] = x;
        }
    }
    __syncthreads();
#pragma unroll
    for (int k = 0; k < N; ++k) v[k] = lds[0][k];
}

// ---------------------------------------------------------------------------
// setup_geo: geo table (int4 per (b,i): {y0, x0, valid?ph:-1, pw}) and task
// descriptors per (b,i,j_idx): {ry0, rx0, rw, rh, jy0, jx0, jph(-1=image), jpw}
// ---------------------------------------------------------------------------
__global__ void setup_geo(const float* __restrict__ boxes,
                          float* __restrict__ ws) {
    int* iws = (int*)ws;
    const int tid = threadIdx.x;
    if (tid < NIMG * NBOX) {
        BoxGeo g = make_geo(boxes + tid * 4);
        ((int4*)(iws + WS_GEO))[tid] =
            make_int4(g.y0, g.x0, g.valid ? g.ph : -1, g.pw);
    }
    for (int t = tid; t < NIMG * NBOX * 17; t += 256) {
        const int bi = t / 17, j_idx = t % 17;
        const int b = bi >> 4, i = bi & 15;
        int d[8] = {0, 0, 0, 0, 0, 0, -1, 0};
        if (j_idx <= i) {
            BoxGeo gi = make_geo(boxes + (b * NBOX + i) * 4);
            if (gi.valid) {
                int ry0 = gi.y0, rx0 = gi.x0;
                int ry1 = gi.y0 + gi.ph, rx1 = gi.x0 + gi.pw;
                bool ok = true;
                if (j_idx >= 1) {
                    BoxGeo gj = make_geo(boxes + (b * NBOX + j_idx - 1) * 4);
                    if (!gj.valid) ok = false;
                    else {
                        ry0 = max(ry0, gj.y0); rx0 = max(rx0, gj.x0);
                        ry1 = min(ry1, gj.y0 + gj.ph);
                        rx1 = min(rx1, gj.x0 + gj.pw);
                        d[4] = gj.y0; d[5] = gj.x0; d[6] = gj.ph; d[7] = gj.pw;
                    }
                }
                if (ok && ry1 > ry0 && rx1 > rx0) {
                    d[0] = ry0; d[1] = rx0; d[2] = rx1 - rx0; d[3] = ry1 - ry0;
                }
            }
        }
        int* o = iws + WS_TASK + t * 8;
#pragma unroll
        for (int k = 0; k < 8; ++k) o[k] = d[k];
    }
}

// ---------------------------------------------------------------------------
// patch mean/std
// ---------------------------------------------------------------------------
__global__ void patch_stats_partial(const float* __restrict__ patch,
                                    float* __restrict__ ws) {
    const int g = blockIdx.x * 256 + threadIdx.x;
    const float4* p4 = (const float4*)patch;
    float4 a = p4[3 * g], b = p4[3 * g + 1], c = p4[3 * g + 2];
    float v[6];
    v[0] = a.x + a.w + b.z + c.y;
    v[1] = a.y + b.x + b.w + c.z;
    v[2] = a.z + b.y + c.x + c.w;
    v[3] = a.x*a.x + a.w*a.w + b.z*b.z + c.y*c.y;
    v[4] = a.y*a.y + b.x*b.x + b.w*b.w + c.z*c.z;
    v[5] = a.z*a.z + b.y*b.y + c.x*c.x + c.w*c.w;
    block_reduceN<6, 4>(v);
    if (threadIdx.x == 0) {
        float* o = ws + WS_PART + blockIdx.x * 6;
#pragma unroll
        for (int k = 0; k < 6; ++k) o[k] = v[k];
    }
}

__global__ void patch_stats_final(float* __restrict__ ws) {
    float v[6];
    const float* p = ws + WS_PART + threadIdx.x * 6;
#pragma unroll
    for (int k = 0; k < 6; ++k) v[k] = p[k];
    block_reduceN<6, 4>(v);
    if (threadIdx.x == 0) {
        const float n = (float)(PSIZE * PSIZE);
#pragma unroll
        for (int c = 0; c < 3; ++c) {
            float m = v[c] / n;
            float var = v[3 + c] / n - m * m;
            ws[WS_PMEAN + c] = m;
            ws[WS_PSTD + c] = sqrtf(fmaxf(var, 0.f)) + 1e-6f;
        }
    }
}

// ---------------------------------------------------------------------------
// pair_sums v3.1: descriptor-driven; empty tasks zero their slot (no memset).
// ---------------------------------------------------------------------------
__launch_bounds__(256)
__global__ void pair_sums(const float* __restrict__ images,
                          const float* __restrict__ patch,
                          float* __restrict__ ws) {
    const int bi = blockIdx.x, j_idx = blockIdx.y, z = blockIdx.z;
    const int i = bi & 15;
    if (j_idx > i) return;                     // slot never read
    if (j_idx >= 1 && z >= ZJ) return;         // slot doesn't exist
    const int slot = (j_idx == 0) ? z : (Z0 + (j_idx - 1) * ZJ + z);
    float* o = ws + WS_PAIR + ((size_t)bi * SLOTS + slot) * 8;

    const int* iws = (const int*)ws;
    const int* d = iws + WS_TASK + (bi * 17 + j_idx) * 8;
    const int rw = d[2];
    if (rw <= 0) {                             // empty task: zero the slot
        if (threadIdx.x == 0) {
#pragma unroll
            for (int k = 0; k < 7; ++k) o[k] = 0.f;
        }
        return;
    }
    const int ry0 = d[0], rx0 = d[1], rh = d[3];
    const int jy0 = d[4], jx0 = d[5], jph = d[6], jpw = d[7];

    __shared__ int4 sgeo[NBOX];
    if (threadIdx.x < NBOX)
        sgeo[threadIdx.x] =
            ((const int4*)(iws + WS_GEO))[(bi >> 4) * NBOX + threadIdx.x];
    __syncthreads();

    const int n = rw * rh;
    const float* img = images + (size_t)(bi >> 4) * IMG_H * IMG_W * 3;
    const float jphf = (float)jph, jpwf = (float)jpw;
    const int nz = (j_idx == 0) ? Z0 : ZJ;

    float v[7] = {0.f, 0.f, 0.f, 0.f, 0.f, 0.f, 0.f};
    for (int t = z * 256 + threadIdx.x; t < n; t += 256 * nz) {
        const int y = ry0 + t / rw;
        const int x = rx0 + t % rw;
        bool inc = true;
        for (int k = j_idx; k < i; ++k) {         // k = j+1 .. i-1
            const int4 g = sgeo[k];
            if (g.z > 0 && y >= g.x && y < g.x + g.z &&
                x >= g.y && x < g.y + g.w) { inc = false; break; }
        }
        if (inc) {
            float s[3];
            if (jph > 0) {
                bsample(patch, y - jy0, x - jx0, jphf, jpwf, s);
            } else {
                const float* p = img + ((size_t)y * IMG_W + x) * 3;
                s[0] = p[0]; s[1] = p[1]; s[2] = p[2];
            }
            v[0] += 1.f;
            v[1] += s[0]; v[2] += s[1]; v[3] += s[2];
            v[4] += s[0]*s[0]; v[5] += s[1]*s[1]; v[6] += s[2]*s[2];
        }
    }
    block_reduceN<7, 4>(v);
    if (threadIdx.x == 0) {
#pragma unroll
        for (int k = 0; k < 7; ++k) o[k] = v[k];
    }
}

// ---------------------------------------------------------------------------
// solve_coeffs: per-image 16-step recurrence. One wave per image.
// ---------------------------------------------------------------------------
__global__ void solve_coeffs(const float* __restrict__ boxes,
                             float* __restrict__ ws) {
    const int b = blockIdx.x;
    const int lane = threadIdx.x;       // 64 threads = 1 wave

    BoxGeo g = make_geo(boxes + (b * NBOX + (lane < NBOX ? lane : NBOX - 1)) * 4);
    float pm[3], ps[3];
#pragma unroll
    for (int c = 0; c < 3; ++c) { pm[c] = ws[WS_PMEAN + c]; ps[c] = ws[WS_PSTD + c]; }

    float sc[3] = {0.f, 0.f, 0.f}, of[3] = {0.f, 0.f, 0.f};

    for (int i = 0; i < NBOX; ++i) {
        const int valid_i = __shfl(g.valid, i, 64);
        if (!valid_i) continue;

        float cnt = 0.f, s1[3] = {0.f,0.f,0.f}, s2[3] = {0.f,0.f,0.f};
        if (lane <= i) {
            const int slot0 = (lane == 0) ? 0 : (Z0 + (lane - 1) * ZJ);
            const int nz = (lane == 0) ? Z0 : ZJ;
            const float* p = ws + WS_PAIR +
                ((size_t)(b * NBOX + i) * SLOTS + slot0) * 8;
            for (int zz = 0; zz < nz; ++zz) {
                cnt   += p[zz*8 + 0];
                s1[0] += p[zz*8 + 1]; s1[1] += p[zz*8 + 2]; s1[2] += p[zz*8 + 3];
                s2[0] += p[zz*8 + 4]; s2[1] += p[zz*8 + 5]; s2[2] += p[zz*8 + 6];
            }
        }
        float ts[3], tq[3];
#pragma unroll
        for (int c = 0; c < 3; ++c) {
            if (lane == 0) { ts[c] = s1[c]; tq[c] = s2[c]; }
            else {
                ts[c] = sc[c] * s1[c] + of[c] * cnt;
                tq[c] = sc[c]*sc[c]*s2[c] + 2.f*sc[c]*of[c]*s1[c] + of[c]*of[c]*cnt;
            }
        }
#pragma unroll
        for (int c = 0; c < 3; ++c) {
#pragma unroll
            for (int off = 16; off > 0; off >>= 1) {
                ts[c] += __shfl_down(ts[c], off, 32);
                tq[c] += __shfl_down(tq[c], off, 32);
            }
        }
        const int phi = __shfl(g.ph, i, 64);
        const int pwi = __shfl(g.pw, i, 64);
        const float cntf = fmaxf((float)(phi * pwi), 1.0f);
        float nsc[3] = {0.f,0.f,0.f}, nof[3] = {0.f,0.f,0.f};
        if (lane == 0) {
#pragma unroll
            for (int c = 0; c < 3; ++c) {
                float mean = ts[c] / cntf;
                float var = tq[c] / cntf - mean * mean;
                float sd = sqrtf(fmaxf(var, 0.f)) + 1e-6f;
                nsc[c] = sd / ps[c];
                nof[c] = mean - pm[c] * nsc[c];
            }
        }
#pragma unroll
        for (int c = 0; c < 3; ++c) {
            float bs = __shfl(nsc[c], 0, 64);
            float bo = __shfl(nof[c], 0, 64);
            if (lane == i + 1) { sc[c] = bs; of[c] = bo; }
            if (lane == 0) {
                ws[WS_COEF + (size_t)(b * NBOX + i) * 8 + c] = bs;
                ws[WS_COEF + (size_t)(b * NBOX + i) * 8 + 3 + c] = bo;
            }
        }
    }
}

// ---------------------------------------------------------------------------
// decal: write only covered pixels. Block (bi, z): pixels of rect_i not
// covered by any later valid box (those are written by that box's decal).
// Mutually exclusive writes -> deterministic.
// ---------------------------------------------------------------------------
__launch_bounds__(256)
__global__ void decal(const float* __restrict__ patch,
                      const float* __restrict__ ws,
                      float* __restrict__ out) {
    const int bi = blockIdx.x;
    const int b = bi >> 4, i = bi & 15;
    const int* iws = (const int*)ws;
    __shared__ int4 sgeo[NBOX];
    __shared__ float scoef[6];
    if (threadIdx.x < NBOX)
        sgeo[threadIdx.x] = ((const int4*)(iws + WS_GEO))[b * NBOX + threadIdx.x];
    if (threadIdx.x >= 32 && threadIdx.x < 38)
        scoef[threadIdx.x - 32] = ws[WS_COEF + (size_t)bi * 8 + (threadIdx.x - 32)];
    __syncthreads();
    const int4 gi = sgeo[i];
    if (gi.z <= 0) return;                     // invalid patch
    const int y0 = gi.x, x0 = gi.y, ph = gi.z, pw = gi.w;
    const int n = ph * pw;
    const float phf = (float)ph, pwf = (float)pw;
    float* img = out + (size_t)b * IMG_H * IMG_W * 3;

    for (int t = blockIdx.y * 256 + threadIdx.x; t < n; t += 256 * 8) {
        const int y = y0 + t / pw;
        const int x = x0 + t % pw;
        bool cov = false;
        for (int k = i + 1; k < NBOX; ++k) {
            const int4 g = sgeo[k];
            if (g.z > 0 && y >= g.x && y < g.x + g.z &&
                x >= g.y && x < g.y + g.w) { cov = true; break; }
        }
        if (!cov) {
            float s[3];
            bsample(patch, y - y0, x - x0, phf, pwf, s);
            float* o = img + ((size_t)y * IMG_W + x) * 3;
            o[0] = s[0] * scoef[0] + scoef[3];
            o[1] = s[1] * scoef[1] + scoef[4];
            o[2] = s[2] * scoef[2] + scoef[5];
        }
    }
}

extern "C" void kernel_launch(void* const* d_in, const int* in_sizes, int n_in,
                              void* d_out, int out_size, void* d_ws, size_t ws_size,
                              hipStream_t stream) {
    const float* images = (const float*)d_in[0];
    const float* boxes  = (const float*)d_in[1];
    const float* patch  = (const float*)d_in[2];
    float* out = (float*)d_out;
    float* ws  = (float*)d_ws;

    setup_geo<<<1, 256, 0, stream>>>(boxes, ws);
    patch_stats_partial<<<RED_BLOCKS, 256, 0, stream>>>(patch, ws);
    patch_stats_final<<<1, RED_BLOCKS, 0, stream>>>(ws);
    // background copy: pure streaming at ~full HBM BW
    hipMemcpyAsync(out, images, (size_t)NIMG * IMG_H * IMG_W * 3 * sizeof(float),
                   hipMemcpyDeviceToDevice, stream);
    pair_sums<<<dim3(NIMG * NBOX, 17, Z0), 256, 0, stream>>>(images, patch, ws);
    solve_coeffs<<<NIMG, 64, 0, stream>>>(boxes, ws);
    decal<<<dim3(NIMG * NBOX, 8), 256, 0, stream>>>(patch, ws, out);
}

// Round 12
// 126.712 us; speedup vs baseline: 1.0632x; 1.0319x over previous
//
#include <hip/hip_runtime.h>
#include <math.h>

#define IMG_H 512
#define IMG_W 512
#define PSIZE 512
#define NIMG 16
#define NBOX 16
#define Z0 8              // z-split for j=-1 (full-rect) tasks
#define ZJ 4              // z-split for j>=0 (intersection) tasks
#define SLOTS 72          // Z0 + NBOX*ZJ partial slots per (b,i)
#define NCOPY 2048        // background-copy chunks
#define CHUNK4 1536       // float4 per copy chunk (6 per thread)
#define MAXITEMS 13824

// workspace layout (float indices; int4-accessed regions are 16B aligned)
#define WS_PMEAN 0                      // 3
#define WS_PSTD  3                      // 3
#define WS_PART  6                      // 256*6 = 1536
#define WS_GEO   1544                   // 256 int4
#define WS_TASK  2568                   // 4352*8 ints
#define WS_TMASK 37384                  // 256 ints
#define WS_COUNT 37640                  // 1 int
#define WS_ITEMS 37644                  // MAXITEMS int4
#define WS_PAIR  92944                  // 256*SLOTS*8 floats
#define WS_COEF  240400                 // 256*8 floats

struct BoxGeo { int y0, x0, ph, pw, valid; };

__device__ __forceinline__ BoxGeo make_geo(const float* bx) {
    float ymin = bx[0], xmin = bx[1], ymax = bx[2], xmax = bx[3];
    float h = ymax - ymin, w = xmax - xmin;
    float pwf = h * 0.3f;            // SCALE
    float phf = 1.0f * pwf;          // ASPECT * pw
    float oy = ymin + h * 0.5f;
    float ox = xmin + w * 0.5f;
    float yp = fmaxf(oy - phf * 0.5f, 0.0f);
    float xp = fmaxf(ox - pwf * 0.5f, 0.0f);
    if (yp + phf > (float)IMG_H) yp = (float)IMG_H - phf;
    if (xp + pwf > (float)IMG_W) xp = (float)IMG_W - pwf;
    BoxGeo g;
    g.y0 = (int)yp; g.x0 = (int)xp;   // tf.cast truncation
    g.ph = (int)phf; g.pw = (int)pwf;
    g.valid = (phf > 60.0f) ? 1 : 0;  // MIN_PATCH_H tested on float ph
    return g;
}

__device__ __forceinline__ void bsample(const float* __restrict__ patch,
                                        int relY, int relX, float phf, float pwf,
                                        float s[3]) {
    float sy = ((float)relY + 0.5f) * (float)PSIZE / phf - 0.5f;
    sy = fminf(fmaxf(sy, 0.0f), (float)(PSIZE - 1));
    float sx = ((float)relX + 0.5f) * (float)PSIZE / pwf - 0.5f;
    sx = fminf(fmaxf(sx, 0.0f), (float)(PSIZE - 1));
    int y0 = (int)floorf(sy);
    int y1 = min(y0 + 1, PSIZE - 1);
    int x0 = (int)floorf(sx);
    int x1 = min(x0 + 1, PSIZE - 1);
    float wy = sy - (float)y0;
    float wx = sx - (float)x0;
    const float* p00 = patch + (y0 * PSIZE + x0) * 3;
    const float* p01 = patch + (y0 * PSIZE + x1) * 3;
    const float* p10 = patch + (y1 * PSIZE + x0) * 3;
    const float* p11 = patch + (y1 * PSIZE + x1) * 3;
#pragma unroll
    for (int c = 0; c < 3; ++c) {
        float top = (1.f - wx) * p00[c] + wx * p01[c];
        float bot = (1.f - wx) * p10[c] + wx * p11[c];
        s[c] = (1.f - wy) * top + wy * bot;
    }
}

template<int N, int NWAVES>
__device__ __forceinline__ void block_reduceN(float v[N]) {
    __shared__ float lds[NWAVES][N];
    const int lane = threadIdx.x & 63;
    const int wave = threadIdx.x >> 6;
    __syncthreads();
#pragma unroll
    for (int k = 0; k < N; ++k) {
#pragma unroll
        for (int off = 32; off > 0; off >>= 1)
            v[k] += __shfl_down(v[k], off, 64);
    }
    if (lane == 0) {
#pragma unroll
        for (int k = 0; k < N; ++k) lds[wave][k] = v[k];
    }
    __syncthreads();
    if (wave == 0) {
#pragma unroll
        for (int k = 0; k < N; ++k) {
            float x = (lane < NWAVES) ? lds[lane][k] : 0.0f;
#pragma unroll
            for (int off = 32; off > 0; off >>= 1)
                x += __shfl_down(x, off, 64);
            if (lane == 0) lds[0][k] = x;
        }
    }
    __syncthreads();
#pragma unroll
    for (int k = 0; k < N; ++k) v[k] = lds[0][k];
}

// ---------------------------------------------------------------------------
// patch mean/std partials (256 blocks x 256 threads, float4)
// ---------------------------------------------------------------------------
__global__ void patch_stats_partial(const float* __restrict__ patch,
                                    float* __restrict__ ws) {
    const int g = blockIdx.x * 256 + threadIdx.x;
    const float4* p4 = (const float4*)patch;
    float4 a = p4[3 * g], b = p4[3 * g + 1], c = p4[3 * g + 2];
    float v[6];
    v[0] = a.x + a.w + b.z + c.y;
    v[1] = a.y + b.x + b.w + c.z;
    v[2] = a.z + b.y + c.x + c.w;
    v[3] = a.x*a.x + a.w*a.w + b.z*b.z + c.y*c.y;
    v[4] = a.y*a.y + b.x*b.x + b.w*b.w + c.z*c.z;
    v[5] = a.z*a.z + b.y*b.y + c.x*c.x + c.w*c.w;
    block_reduceN<6, 4>(v);
    if (threadIdx.x == 0) {
        float* o = ws + WS_PART + blockIdx.x * 6;
#pragma unroll
        for (int k = 0; k < 6; ++k) o[k] = v[k];
    }
}

// ---------------------------------------------------------------------------
// prep (1 block, 256 thr): stats final + geo + task descriptors + compacted
// work-item list + per-(b,i) nonempty-j bitmask. Append order nondeterministic
// but each item writes a unique slot -> deterministic output.
// ---------------------------------------------------------------------------
__global__ void prep(const float* __restrict__ boxes, float* __restrict__ ws) {
    const int tid = threadIdx.x;
    int* iws = (int*)ws;
    __shared__ int lmask[NIMG * NBOX];
    __shared__ int sCnt;
    if (tid == 0) sCnt = 0;
    lmask[tid] = 0;

    // stats final
    float v[6];
    const float* pp = ws + WS_PART + tid * 6;
#pragma unroll
    for (int k = 0; k < 6; ++k) v[k] = pp[k];
    block_reduceN<6, 4>(v);
    if (tid == 0) {
        const float n = (float)(PSIZE * PSIZE);
#pragma unroll
        for (int c = 0; c < 3; ++c) {
            float m = v[c] / n;
            float var = v[3 + c] / n - m * m;
            ws[WS_PMEAN + c] = m;
            ws[WS_PSTD + c] = sqrtf(fmaxf(var, 0.f)) + 1e-6f;
        }
    }

    // geo table
    BoxGeo g0 = make_geo(boxes + tid * 4);
    ((int4*)(iws + WS_GEO))[tid] =
        make_int4(g0.y0, g0.x0, g0.valid ? g0.ph : -1, g0.pw);
    __syncthreads();

    // task descriptors + item compaction
    for (int t = tid; t < NIMG * NBOX * 17; t += 256) {
        const int bi = t / 17, j_idx = t % 17;
        const int b = bi >> 4, i = bi & 15;
        int d[8] = {0, 0, 0, 0, 0, 0, -1, 0};
        if (j_idx <= i) {
            BoxGeo gi = make_geo(boxes + (b * NBOX + i) * 4);
            if (gi.valid) {
                int ry0 = gi.y0, rx0 = gi.x0;
                int ry1 = gi.y0 + gi.ph, rx1 = gi.x0 + gi.pw;
                bool ok = true;
                if (j_idx >= 1) {
                    BoxGeo gj = make_geo(boxes + (b * NBOX + j_idx - 1) * 4);
                    if (!gj.valid) ok = false;
                    else {
                        ry0 = max(ry0, gj.y0); rx0 = max(rx0, gj.x0);
                        ry1 = min(ry1, gj.y0 + gj.ph);
                        rx1 = min(rx1, gj.x0 + gj.pw);
                        d[4] = gj.y0; d[5] = gj.x0; d[6] = gj.ph; d[7] = gj.pw;
                    }
                }
                if (ok && ry1 > ry0 && rx1 > rx0) {
                    d[0] = ry0; d[1] = rx0; d[2] = rx1 - rx0; d[3] = ry1 - ry0;
                }
            }
        }
        int* o = iws + WS_TASK + t * 8;
#pragma unroll
        for (int k = 0; k < 8; ++k) o[k] = d[k];
        if (d[2] > 0) {
            atomicOr(&lmask[bi], 1 << j_idx);
            const int nz = (j_idx == 0) ? Z0 : ZJ;
            const int base = atomicAdd(&sCnt, nz);
            for (int z = 0; z < nz; ++z)
                ((int4*)(iws + WS_ITEMS))[base + z] = make_int4(bi, j_idx, z, 0);
        }
    }
    __syncthreads();
    iws[WS_TMASK + tid] = lmask[tid];
    if (tid == 0) iws[WS_COUNT] = sCnt;
}

// ---------------------------------------------------------------------------
// fused_main: grid-stride over [NCOPY background-copy chunks | pair items].
// Copy (BW-bound) overlaps pair scans (latency-bound).
// ---------------------------------------------------------------------------
__launch_bounds__(256)
__global__ void fused_main(const float* __restrict__ images,
                           const float* __restrict__ patch,
                           float* __restrict__ ws,
                           float* __restrict__ out) {
    const int* iws = (const int*)ws;
    const int total = NCOPY + iws[WS_COUNT];
    __shared__ int4 sgeo[NBOX];

    for (int it = blockIdx.x; it < total; it += gridDim.x) {
        if (it < NCOPY) {
            const float4* s4 = (const float4*)images;
            float4* d4 = (float4*)out;
            const int base = it * CHUNK4 + threadIdx.x;
#pragma unroll
            for (int u = 0; u < 6; ++u)
                d4[base + u * 256] = s4[base + u * 256];
            continue;
        }
        const int4 e = ((const int4*)(iws + WS_ITEMS))[it - NCOPY];
        const int bi = e.x, j_idx = e.y, z = e.z;
        const int i = bi & 15;
        const int* d = iws + WS_TASK + (bi * 17 + j_idx) * 8;
        const int ry0 = d[0], rx0 = d[1], rw = d[2], rh = d[3];
        const int jy0 = d[4], jx0 = d[5], jph = d[6], jpw = d[7];

        if (threadIdx.x < NBOX)
            sgeo[threadIdx.x] =
                ((const int4*)(iws + WS_GEO))[(bi >> 4) * NBOX + threadIdx.x];
        __syncthreads();

        const int n = rw * rh;
        const float* img = images + (size_t)(bi >> 4) * IMG_H * IMG_W * 3;
        const float jphf = (float)jph, jpwf = (float)jpw;
        const int nz = (j_idx == 0) ? Z0 : ZJ;

        float v[7] = {0.f, 0.f, 0.f, 0.f, 0.f, 0.f, 0.f};
        for (int t = z * 256 + threadIdx.x; t < n; t += 256 * nz) {
            const int y = ry0 + t / rw;
            const int x = rx0 + t % rw;
            bool inc = true;
            for (int k = j_idx; k < i; ++k) {      // k = j+1 .. i-1
                const int4 gk = sgeo[k];
                if (gk.z > 0 && y >= gk.x && y < gk.x + gk.z &&
                    x >= gk.y && x < gk.y + gk.w) { inc = false; break; }
            }
            if (inc) {
                float s[3];
                if (jph > 0) {
                    bsample(patch, y - jy0, x - jx0, jphf, jpwf, s);
                } else {
                    const float* p = img + ((size_t)y * IMG_W + x) * 3;
                    s[0] = p[0]; s[1] = p[1]; s[2] = p[2];
                }
                v[0] += 1.f;
                v[1] += s[0]; v[2] += s[1]; v[3] += s[2];
                v[4] += s[0]*s[0]; v[5] += s[1]*s[1]; v[6] += s[2]*s[2];
            }
        }
        block_reduceN<7, 4>(v);
        if (threadIdx.x == 0) {
            const int slot = (j_idx == 0) ? z : (Z0 + (j_idx - 1) * ZJ + z);
            float* o = ws + WS_PAIR + ((size_t)bi * SLOTS + slot) * 8;
#pragma unroll
            for (int k = 0; k < 7; ++k) o[k] = v[k];
        }
    }
}

// ---------------------------------------------------------------------------
// solve_coeffs: per-image 16-step recurrence; bitmask guards empty-j slots.
// ---------------------------------------------------------------------------
__global__ void solve_coeffs(const float* __restrict__ boxes,
                             float* __restrict__ ws) {
    const int b = blockIdx.x;
    const int lane = threadIdx.x;       // 64 threads = 1 wave
    const int* iws = (const int*)ws;

    BoxGeo g = make_geo(boxes + (b * NBOX + (lane < NBOX ? lane : NBOX - 1)) * 4);
    float pm[3], ps[3];
#pragma unroll
    for (int c = 0; c < 3; ++c) { pm[c] = ws[WS_PMEAN + c]; ps[c] = ws[WS_PSTD + c]; }

    float sc[3] = {0.f, 0.f, 0.f}, of[3] = {0.f, 0.f, 0.f};

    for (int i = 0; i < NBOX; ++i) {
        const int valid_i = __shfl(g.valid, i, 64);
        if (!valid_i) continue;
        const int mask = iws[WS_TMASK + b * NBOX + i];

        float cnt = 0.f, s1[3] = {0.f,0.f,0.f}, s2[3] = {0.f,0.f,0.f};
        if (lane <= i && ((mask >> lane) & 1)) {
            const int slot0 = (lane == 0) ? 0 : (Z0 + (lane - 1) * ZJ);
            const int nz = (lane == 0) ? Z0 : ZJ;
            const float* p = ws + WS_PAIR +
                ((size_t)(b * NBOX + i) * SLOTS + slot0) * 8;
            for (int zz = 0; zz < nz; ++zz) {
                cnt   += p[zz*8 + 0];
                s1[0] += p[zz*8 + 1]; s1[1] += p[zz*8 + 2]; s1[2] += p[zz*8 + 3];
                s2[0] += p[zz*8 + 4]; s2[1] += p[zz*8 + 5]; s2[2] += p[zz*8 + 6];
            }
        }
        float ts[3], tq[3];
#pragma unroll
        for (int c = 0; c < 3; ++c) {
            if (lane == 0) { ts[c] = s1[c]; tq[c] = s2[c]; }
            else {
                ts[c] = sc[c] * s1[c] + of[c] * cnt;
                tq[c] = sc[c]*sc[c]*s2[c] + 2.f*sc[c]*of[c]*s1[c] + of[c]*of[c]*cnt;
            }
        }
#pragma unroll
        for (int c = 0; c < 3; ++c) {
#pragma unroll
            for (int off = 16; off > 0; off >>= 1) {
                ts[c] += __shfl_down(ts[c], off, 32);
                tq[c] += __shfl_down(tq[c], off, 32);
            }
        }
        const int phi = __shfl(g.ph, i, 64);
        const int pwi = __shfl(g.pw, i, 64);
        const float cntf = fmaxf((float)(phi * pwi), 1.0f);
        float nsc[3] = {0.f,0.f,0.f}, nof[3] = {0.f,0.f,0.f};
        if (lane == 0) {
#pragma unroll
            for (int c = 0; c < 3; ++c) {
                float mean = ts[c] / cntf;
                float var = tq[c] / cntf - mean * mean;
                float sd = sqrtf(fmaxf(var, 0.f)) + 1e-6f;
                nsc[c] = sd / ps[c];
                nof[c] = mean - pm[c] * nsc[c];
            }
        }
#pragma unroll
        for (int c = 0; c < 3; ++c) {
            float bs = __shfl(nsc[c], 0, 64);
            float bo = __shfl(nof[c], 0, 64);
            if (lane == i + 1) { sc[c] = bs; of[c] = bo; }
            if (lane == 0) {
                ws[WS_COEF + (size_t)(b * NBOX + i) * 8 + c] = bs;
                ws[WS_COEF + (size_t)(b * NBOX + i) * 8 + 3 + c] = bo;
            }
        }
    }
}

// ---------------------------------------------------------------------------
// decal: write only covered pixels (last-coverer exclusive regions).
// ---------------------------------------------------------------------------
__launch_bounds__(256)
__global__ void decal(const float* __restrict__ patch,
                      const float* __restrict__ ws,
                      float* __restrict__ out) {
    const int bi = blockIdx.x;
    const int b = bi >> 4, i = bi & 15;
    const int* iws = (const int*)ws;
    __shared__ int4 sgeo[NBOX];
    __shared__ float scoef[6];
    if (threadIdx.x < NBOX)
        sgeo[threadIdx.x] = ((const int4*)(iws + WS_GEO))[b * NBOX + threadIdx.x];
    if (threadIdx.x >= 32 && threadIdx.x < 38)
        scoef[threadIdx.x - 32] = ws[WS_COEF + (size_t)bi * 8 + (threadIdx.x - 32)];
    __syncthreads();
    const int4 gi = sgeo[i];
    if (gi.z <= 0) return;                     // invalid patch
    const int y0 = gi.x, x0 = gi.y, ph = gi.z, pw = gi.w;
    const int n = ph * pw;
    const float phf = (float)ph, pwf = (float)pw;
    float* img = out + (size_t)b * IMG_H * IMG_W * 3;

    for (int t = blockIdx.y * 256 + threadIdx.x; t < n; t += 256 * 8) {
        const int y = y0 + t / pw;
        const int x = x0 + t % pw;
        bool cov = false;
        for (int k = i + 1; k < NBOX; ++k) {
            const int4 g = sgeo[k];
            if (g.z > 0 && y >= g.x && y < g.x + g.z &&
                x >= g.y && x < g.y + g.w) { cov = true; break; }
        }
        if (!cov) {
            float s[3];
            bsample(patch, y - y0, x - x0, phf, pwf, s);
            float* o = img + ((size_t)y * IMG_W + x) * 3;
            o[0] = s[0] * scoef[0] + scoef[3];
            o[1] = s[1] * scoef[1] + scoef[4];
            o[2] = s[2] * scoef[2] + scoef[5];
        }
    }
}

extern "C" void kernel_launch(void* const* d_in, const int* in_sizes, int n_in,
                              void* d_out, int out_size, void* d_ws, size_t ws_size,
                              hipStream_t stream) {
    const float* images = (const float*)d_in[0];
    const float* boxes  = (const float*)d_in[1];
    const float* patch  = (const float*)d_in[2];
    float* out = (float*)d_out;
    float* ws  = (float*)d_ws;

    patch_stats_partial<<<256, 256, 0, stream>>>(patch, ws);
    prep<<<1, 256, 0, stream>>>(boxes, ws);
    fused_main<<<4096, 256, 0, stream>>>(images, patch, ws, out);
    solve_coeffs<<<NIMG, 64, 0, stream>>>(boxes, ws);
    decal<<<dim3(NIMG * NBOX, 8), 256, 0, stream>>>(patch, ws, out);
}

// Round 14
// 102.824 us; speedup vs baseline: 1.3102x; 1.2323x over previous
//
#include <hip/hip_runtime.h>
#include <math.h>

#define IMG_H 512
#define IMG_W 512
#define PSIZE 512
#define NIMG 16
#define NBOX 16
#define RED_BLOCKS 256
#define ZSPLIT 4

// workspace layout (floats)
#define WS_PMEAN 0                                        // 3
#define WS_PSTD  3                                        // 3
#define WS_PART  6                                        // RED_BLOCKS*6
#define WS_PAIR  (6 + RED_BLOCKS * 6)                     // [b][i][j 0..16][z][8]
#define WS_COEF  (WS_PAIR + NIMG * NBOX * 17 * ZSPLIT * 8)// [b][i][8]

struct BoxGeo { int y0, x0, ph, pw, valid; };

__device__ __forceinline__ BoxGeo make_geo(const float* bx) {
    float ymin = bx[0], xmin = bx[1], ymax = bx[2], xmax = bx[3];
    float h = ymax - ymin, w = xmax - xmin;
    float pwf = h * 0.3f;            // SCALE
    float phf = 1.0f * pwf;          // ASPECT * pw
    float oy = ymin + h * 0.5f;
    float ox = xmin + w * 0.5f;
    float yp = fmaxf(oy - phf * 0.5f, 0.0f);
    float xp = fmaxf(ox - pwf * 0.5f, 0.0f);
    if (yp + phf > (float)IMG_H) yp = (float)IMG_H - phf;
    if (xp + pwf > (float)IMG_W) xp = (float)IMG_W - pwf;
    BoxGeo g;
    g.y0 = (int)yp; g.x0 = (int)xp;   // tf.cast truncation
    g.ph = (int)phf; g.pw = (int)pwf;
    g.valid = (phf > 60.0f) ? 1 : 0;  // MIN_PATCH_H tested on float ph
    return g;
}

__device__ __forceinline__ void bsample(const float* __restrict__ patch,
                                        int relY, int relX, float phf, float pwf,
                                        float s[3]) {
    float sy = ((float)relY + 0.5f) * (float)PSIZE / phf - 0.5f;
    sy = fminf(fmaxf(sy, 0.0f), (float)(PSIZE - 1));
    float sx = ((float)relX + 0.5f) * (float)PSIZE / pwf - 0.5f;
    sx = fminf(fmaxf(sx, 0.0f), (float)(PSIZE - 1));
    int y0 = (int)floorf(sy);
    int y1 = min(y0 + 1, PSIZE - 1);
    int x0 = (int)floorf(sx);
    int x1 = min(x0 + 1, PSIZE - 1);
    float wy = sy - (float)y0;
    float wx = sx - (float)x0;
    const float* p00 = patch + (y0 * PSIZE + x0) * 3;
    const float* p01 = patch + (y0 * PSIZE + x1) * 3;
    const float* p10 = patch + (y1 * PSIZE + x0) * 3;
    const float* p11 = patch + (y1 * PSIZE + x1) * 3;
#pragma unroll
    for (int c = 0; c < 3; ++c) {
        float top = (1.f - wx) * p00[c] + wx * p01[c];
        float bot = (1.f - wx) * p10[c] + wx * p11[c];
        s[c] = (1.f - wy) * top + wy * bot;
    }
}

template<int N, int NWAVES>
__device__ __forceinline__ void block_reduceN(float v[N]) {
    __shared__ float lds[NWAVES][N];
    const int lane = threadIdx.x & 63;
    const int wave = threadIdx.x >> 6;
    __syncthreads();
#pragma unroll
    for (int k = 0; k < N; ++k) {
#pragma unroll
        for (int off = 32; off > 0; off >>= 1)
            v[k] += __shfl_down(v[k], off, 64);
    }
    if (lane == 0) {
#pragma unroll
        for (int k = 0; k < N; ++k) lds[wave][k] = v[k];
    }
    __syncthreads();
    if (wave == 0) {
#pragma unroll
        for (int k = 0; k < N; ++k) {
            float x = (lane < NWAVES) ? lds[lane][k] : 0.0f;
#pragma unroll
            for (int off = 32; off > 0; off >>= 1)
                x += __shfl_down(x, off, 64);
            if (lane == 0) lds[0][k] = x;
        }
    }
    __syncthreads();
#pragma unroll
    for (int k = 0; k < N; ++k) v[k] = lds[0][k];
}

// ---------------------------------------------------------------------------
// patch mean/std — vectorized: thread g loads float4[3g..3g+2] = 4 RGB pixels
// ---------------------------------------------------------------------------
__global__ void patch_stats_partial(const float* __restrict__ patch,
                                    float* __restrict__ ws) {
    const int g = blockIdx.x * 256 + threadIdx.x;   // 0..65535
    const float4* p4 = (const float4*)patch;
    float4 a = p4[3 * g], b = p4[3 * g + 1], c = p4[3 * g + 2];
    float v[6];
    v[0] = a.x + a.w + b.z + c.y;
    v[1] = a.y + b.x + b.w + c.z;
    v[2] = a.z + b.y + c.x + c.w;
    v[3] = a.x*a.x + a.w*a.w + b.z*b.z + c.y*c.y;
    v[4] = a.y*a.y + b.x*b.x + b.w*b.w + c.z*c.z;
    v[5] = a.z*a.z + b.y*b.y + c.x*c.x + c.w*c.w;
    block_reduceN<6, 4>(v);
    if (threadIdx.x == 0) {
        float* o = ws + WS_PART + blockIdx.x * 6;
#pragma unroll
        for (int k = 0; k < 6; ++k) o[k] = v[k];
    }
}

__global__ void patch_stats_final(float* __restrict__ ws) {
    float v[6];
    const float* p = ws + WS_PART + threadIdx.x * 6;
#pragma unroll
    for (int k = 0; k < 6; ++k) v[k] = p[k];
    block_reduceN<6, 4>(v);
    if (threadIdx.x == 0) {
        const float n = (float)(PSIZE * PSIZE);
#pragma unroll
        for (int c = 0; c < 3; ++c) {
            float m = v[c] / n;
            float var = v[3 + c] / n - m * m;
            ws[WS_PMEAN + c] = m;
            ws[WS_PSTD + c] = sqrtf(fmaxf(var, 0.f)) + 1e-6f;
        }
    }
}

// ---------------------------------------------------------------------------
// Kernel A: pair sums. Empty/invalid tasks exit BEFORE any LDS staging/sync.
// block = (b*16+i, j_idx 0..16, z). j = j_idx-1 (-1 = original image).
// ---------------------------------------------------------------------------
__launch_bounds__(256)
__global__ void pair_sums(const float* __restrict__ images,
                          const float* __restrict__ boxes,
                          const float* __restrict__ patch,
                          float* __restrict__ ws) {
    const int bi = blockIdx.x;
    const int j_idx = blockIdx.y;
    const int z = blockIdx.z;
    const int b = bi >> 4, i = bi & 15;
    if (j_idx > i) return;               // slot never read

    // register-only geometry; all threads redundantly (broadcast loads)
    const BoxGeo gi = make_geo(boxes + (b * NBOX + i) * 4);
    if (!gi.valid) return;               // solve skips invalid i entirely

    float* o = ws + WS_PAIR + (((size_t)(b * NBOX + i) * 17 + j_idx) * ZSPLIT + z) * 8;

    int ry0 = gi.y0, rx0 = gi.x0;
    int ry1 = gi.y0 + gi.ph, rx1 = gi.x0 + gi.pw;
    int jy0 = 0, jx0 = 0, jph = -1;
    float jphf = 1.f, jpwf = 1.f;
    if (j_idx >= 1) {
        const BoxGeo gj = make_geo(boxes + (b * NBOX + j_idx - 1) * 4);
        if (!gj.valid) {
            if (threadIdx.x == 0) { for (int k = 0; k < 7; ++k) o[k] = 0.f; }
            return;
        }
        ry0 = max(ry0, gj.y0); rx0 = max(rx0, gj.x0);
        ry1 = min(ry1, gj.y0 + gj.ph); rx1 = min(rx1, gj.x0 + gj.pw);
        jy0 = gj.y0; jx0 = gj.x0; jph = gj.ph;
        jphf = (float)gj.ph; jpwf = (float)gj.pw;
    }
    const int rw = rx1 - rx0, rh = ry1 - ry0;
    if (rw <= 0 || rh <= 0) {
        if (threadIdx.x == 0) { for (int k = 0; k < 7; ++k) o[k] = 0.f; }
        return;
    }

    // only non-empty tasks stage the geo table for the occlusion loop
    __shared__ BoxGeo geo[NBOX];
    if (threadIdx.x < NBOX)
        geo[threadIdx.x] = make_geo(boxes + (b * NBOX + threadIdx.x) * 4);
    __syncthreads();

    const int n = rw * rh;
    const float* img = images + (size_t)b * IMG_H * IMG_W * 3;

    float v[7] = {0.f, 0.f, 0.f, 0.f, 0.f, 0.f, 0.f};
    for (int t = z * 256 + threadIdx.x; t < n; t += 256 * ZSPLIT) {
        const int y = ry0 + t / rw;
        const int x = rx0 + t % rw;
        bool inc = true;
        for (int k = j_idx; k < i; ++k) {      // k = j+1 .. i-1
            const BoxGeo gk = geo[k];
            if (gk.valid && y >= gk.y0 && y < gk.y0 + gk.ph &&
                x >= gk.x0 && x < gk.x0 + gk.pw) { inc = false; break; }
        }
        if (inc) {
            float s[3];
            if (jph > 0) {
                bsample(patch, y - jy0, x - jx0, jphf, jpwf, s);
            } else {
                const float* p = img + ((size_t)y * IMG_W + x) * 3;
                s[0] = p[0]; s[1] = p[1]; s[2] = p[2];
            }
            v[0] += 1.f;
            v[1] += s[0]; v[2] += s[1]; v[3] += s[2];
            v[4] += s[0]*s[0]; v[5] += s[1]*s[1]; v[6] += s[2]*s[2];
        }
    }
    block_reduceN<7, 4>(v);
    if (threadIdx.x == 0) {
#pragma unroll
        for (int k = 0; k < 7; ++k) o[k] = v[k];
    }
}

// ---------------------------------------------------------------------------
// Kernel B: per-image 16-step recurrence. One wave per image.
// ---------------------------------------------------------------------------
__global__ void solve_coeffs(const float* __restrict__ boxes,
                             float* __restrict__ ws) {
    const int b = blockIdx.x;
    const int lane = threadIdx.x;       // 64 threads = 1 wave

    BoxGeo g = make_geo(boxes + (b * NBOX + (lane < NBOX ? lane : NBOX - 1)) * 4);
    float pm[3], ps[3];
#pragma unroll
    for (int c = 0; c < 3; ++c) { pm[c] = ws[WS_PMEAN + c]; ps[c] = ws[WS_PSTD + c]; }

    float sc[3] = {0.f, 0.f, 0.f}, of[3] = {0.f, 0.f, 0.f};

    for (int i = 0; i < NBOX; ++i) {
        const int valid_i = __shfl(g.valid, i, 64);
        if (!valid_i) continue;

        float cnt = 0.f, s1[3] = {0.f,0.f,0.f}, s2[3] = {0.f,0.f,0.f};
        if (lane <= i) {
            const float* p = ws + WS_PAIR +
                ((size_t)(b * NBOX + i) * 17 + lane) * ZSPLIT * 8;
#pragma unroll
            for (int zz = 0; zz < ZSPLIT; ++zz) {
                cnt   += p[zz*8 + 0];
                s1[0] += p[zz*8 + 1]; s1[1] += p[zz*8 + 2]; s1[2] += p[zz*8 + 3];
                s2[0] += p[zz*8 + 4]; s2[1] += p[zz*8 + 5]; s2[2] += p[zz*8 + 6];
            }
        }
        float ts[3], tq[3];
#pragma unroll
        for (int c = 0; c < 3; ++c) {
            if (lane == 0) { ts[c] = s1[c]; tq[c] = s2[c]; }
            else {
                ts[c] = sc[c] * s1[c] + of[c] * cnt;
                tq[c] = sc[c]*sc[c]*s2[c] + 2.f*sc[c]*of[c]*s1[c] + of[c]*of[c]*cnt;
            }
        }
#pragma unroll
        for (int c = 0; c < 3; ++c) {
#pragma unroll
            for (int off = 16; off > 0; off >>= 1) {
                ts[c] += __shfl_down(ts[c], off, 32);
                tq[c] += __shfl_down(tq[c], off, 32);
            }
        }
        const int phi = __shfl(g.ph, i, 64);
        const int pwi = __shfl(g.pw, i, 64);
        const float cntf = fmaxf((float)(phi * pwi), 1.0f);
        float nsc[3] = {0.f,0.f,0.f}, nof[3] = {0.f,0.f,0.f};
        if (lane == 0) {
#pragma unroll
            for (int c = 0; c < 3; ++c) {
                float mean = ts[c] / cntf;
                float var = tq[c] / cntf - mean * mean;
                float sd = sqrtf(fmaxf(var, 0.f)) + 1e-6f;
                nsc[c] = sd / ps[c];
                nof[c] = mean - pm[c] * nsc[c];
            }
        }
#pragma unroll
        for (int c = 0; c < 3; ++c) {
            float bs = __shfl(nsc[c], 0, 64);
            float bo = __shfl(nof[c], 0, 64);
            if (lane == i + 1) { sc[c] = bs; of[c] = bo; }
            if (lane == 0) {
                ws[WS_COEF + (size_t)(b * NBOX + i) * 8 + c] = bs;
                ws[WS_COEF + (size_t)(b * NBOX + i) * 8 + 3 + c] = bo;
            }
        }
    }
}

// ---------------------------------------------------------------------------
// Kernel C: render v3. Phase 1: unconditional streaming float4 copy.
// Phase 2 (strips with candidate boxes): overwrite covered pixels.
// ---------------------------------------------------------------------------
__launch_bounds__(256)
__global__ void render(const float* __restrict__ images,
                       const float* __restrict__ boxes,
                       const float* __restrict__ patch,
                       const float* __restrict__ ws,
                       float* __restrict__ out) {
    const int b = blockIdx.y;
    const int tid = threadIdx.x;
    __shared__ BoxGeo geo[NBOX];
    __shared__ float coef[NBOX][6];
    __shared__ int smask;

    const int strip_y0 = blockIdx.x * 2;          // rows strip_y0, strip_y0+1

    if (tid == 0) smask = 0;
    if (tid < NBOX)
        geo[tid] = make_geo(boxes + (b * NBOX + tid) * 4);
    __syncthreads();
    if (tid < NBOX) {
        const BoxGeo g = geo[tid];
        if (g.valid && g.y0 < strip_y0 + 2 && g.y0 + g.ph > strip_y0)
            atomicOr(&smask, 1 << tid);
    }

    // phase 1: unconditional streaming copy of this block's quads
    const int q = blockIdx.x * 256 + tid;         // quad index
    const float4* src = (const float4*)(images + (size_t)b * IMG_H * IMG_W * 3);
    float4* dst = (float4*)(out + (size_t)b * IMG_H * IMG_W * 3);
    dst[3*q]     = src[3*q];
    dst[3*q + 1] = src[3*q + 1];
    dst[3*q + 2] = src[3*q + 2];

    __syncthreads();                              // smask ready
    const int mask = smask;
    if (mask == 0) return;                        // no box touches this strip

    if (tid < NBOX * 6) {
        int i = tid / 6, c = tid % 6;
        coef[i][c] = ws[WS_COEF + (size_t)(b * NBOX + i) * 8 + c];
    }
    __syncthreads();

    // phase 2: overwrite covered pixels (last valid coverer wins)
    const int p0 = q << 2;
    const int y = p0 >> 9, x0 = p0 & 511;
    float* outp = out + (size_t)b * IMG_H * IMG_W * 3;

#pragma unroll
    for (int u = 0; u < 4; ++u) {
        const int x = x0 + u;
        int last = -1;
        int m = mask;
        while (m) {
            const int j = 31 - __clz(m);
            const BoxGeo g = geo[j];
            if (y >= g.y0 && y < g.y0 + g.ph && x >= g.x0 && x < g.x0 + g.pw) {
                last = j; break;
            }
            m &= ~(1 << j);
        }
        if (last >= 0) {
            const BoxGeo g = geo[last];
            float s[3];
            bsample(patch, y - g.y0, x - g.x0, (float)g.ph, (float)g.pw, s);
            float* o = outp + ((size_t)y * IMG_W + x) * 3;
            o[0] = s[0] * coef[last][0] + coef[last][3];
            o[1] = s[1] * coef[last][1] + coef[last][4];
            o[2] = s[2] * coef[last][2] + coef[last][5];
        }
    }
}

extern "C" void kernel_launch(void* const* d_in, const int* in_sizes, int n_in,
                              void* d_out, int out_size, void* d_ws, size_t ws_size,
                              hipStream_t stream) {
    const float* images = (const float*)d_in[0];
    const float* boxes  = (const float*)d_in[1];
    const float* patch  = (const float*)d_in[2];
    float* out = (float*)d_out;
    float* ws  = (float*)d_ws;

    patch_stats_partial<<<RED_BLOCKS, 256, 0, stream>>>(patch, ws);
    patch_stats_final<<<1, RED_BLOCKS, 0, stream>>>(ws);
    pair_sums<<<dim3(NIMG * NBOX, 17, ZSPLIT), 256, 0, stream>>>(images, boxes, patch, ws);
    solve_coeffs<<<NIMG, 64, 0, stream>>>(boxes, ws);
    render<<<dim3(IMG_H * IMG_W / 4 / 256, NIMG), 256, 0, stream>>>(images, boxes, patch, ws, out);
}